// Round 5
// baseline (480.891 us; speedup 1.0000x reference)
//
#include <hip/hip_runtime.h>
#include <math.h>

// EmformerAttention MI355X — round 4: async-DMA triple-buffered MFMA attention
// (global_load_lds + XOR-swizzled LDS + raw-barrier pipeline), vt folded into
// KV epilogue. U=512 B=16 D=512 H=8 HD=64 R=32 S=16 M=32 -> Q=560 KV=576 N=128

#define NEG_INF_F (-100000000.0f)
#define SCALE_F   (0.125f)

typedef short  short8 __attribute__((ext_vector_type(8)));
typedef float  f32x4  __attribute__((ext_vector_type(4)));
typedef unsigned short u16x4 __attribute__((ext_vector_type(4)));
typedef unsigned short u16x8 __attribute__((ext_vector_type(8)));

__device__ __forceinline__ unsigned short f2b(float f) {
    unsigned int u = __builtin_bit_cast(unsigned int, f);
    u = u + 0x7FFFu + ((u >> 16) & 1u);
    return (unsigned short)(u >> 16);
}
__device__ __forceinline__ float b2f(unsigned short h) {
    unsigned int u = ((unsigned int)h) << 16;
    return __builtin_bit_cast(float, u);
}
// async global->LDS DMA, 16B per lane; LDS dest = wave-uniform base + lane*16
__device__ __forceinline__ void dma16(const unsigned short* gp, unsigned short* lp) {
    __builtin_amdgcn_global_load_lds(
        (const __attribute__((address_space(1))) unsigned int*)(gp),
        (__attribute__((address_space(3))) unsigned int*)(lp), 16, 0, 0);
}

// ---------------------------------------------------------------------------
__global__ __launch_bounds__(256) void detect_mask_kernel(
    const unsigned int* __restrict__ m, int nwords, int* __restrict__ flags) {
    __shared__ int fF, fG;
    if (threadIdx.x == 0) { fF = 0; fG = 0; }
    __syncthreads();
    int lF = 0, lG = 0;
    for (int i = blockIdx.x * 256 + threadIdx.x; i < nwords; i += gridDim.x * 256) {
        unsigned int w = m[i];
        if (w == 0x3F800000u)      lF = 1;
        else if (w > 1u)           lG = 1;
    }
    if (lF) atomicOr(&fF, 1);
    if (lG) atomicOr(&fG, 1);
    __syncthreads();
    if (threadIdx.x == 0) {
        if (fF) atomicOr(&flags[0], 1);
        if (fG) atomicOr(&flags[1], 1);
    }
}

// ---------------------------------------------------------------------------
__global__ __launch_bounds__(256) void conv9_kernel(
    const float* s0, const float* s1, const float* s2, const float* s3,
    const float* s4, const float* s5, const float* s6, const float* s7,
    const float* s8,
    unsigned short* d0, unsigned short* d1, unsigned short* d2,
    unsigned short* d3, unsigned short* d4, unsigned short* d5,
    unsigned short* d6, unsigned short* d7, unsigned short* d8,
    int n0, int n1, int n2, int n3, int n4, int n5, int n6, int n7, int n8)
{
    const float* ss[9] = {s0, s1, s2, s3, s4, s5, s6, s7, s8};
    unsigned short* dd[9] = {d0, d1, d2, d3, d4, d5, d6, d7, d8};
    int nn[9] = {n0, n1, n2, n3, n4, n5, n6, n7, n8};
    const int a = blockIdx.y;
    const float* s = ss[a];
    unsigned short* d = dd[a];
    const int nq = nn[a] >> 2;
    for (int i = blockIdx.x * 256 + threadIdx.x; i < nq; i += gridDim.x * 256) {
        float4 v = *(const float4*)(s + (size_t)i * 4);
        u16x4 o = {f2b(v.x), f2b(v.y), f2b(v.z), f2b(v.w)};
        *(u16x4*)(d + (size_t)i * 4) = o;
    }
}

// ---------------------------------------------------------------------------
// bf16 MFMA GEMM. K=512, BK=32, BM=BN=128, 4 waves.
// mode 0: out-proj (clamp rows>=clampStart); mode 1: KV (key fp32+bf16,
// val fp32 + VT bf16 [n][hd][576]); mode 2: Q (Qu/Qv bf16); mode 3: pos.
__global__ __launch_bounds__(256) void gemm_mfma(
    const unsigned short* __restrict__ a0, const unsigned short* __restrict__ a1,
    const unsigned short* __restrict__ a2,
    int rb1, int rb2, int Mrows,
    const unsigned short* __restrict__ Wt, const float* __restrict__ bias,
    float* __restrict__ out0, float* __restrict__ out1,
    unsigned short* __restrict__ auxU, unsigned short* __restrict__ auxV,
    const float* __restrict__ pbu, const float* __restrict__ pbv,
    int mode, int clampStart)
{
    __shared__ unsigned short As[128 * 40];
    __shared__ unsigned short Ws[128 * 40];

    const int tid = threadIdx.x;
    const int w = tid >> 6, lane = tid & 63;
    const int l15 = lane & 15, l4 = lane >> 4;
    const int wm = (w & 1) * 64, wn = (w >> 1) * 64;
    const int bm = blockIdx.y * 128, bn = blockIdx.x * 128;

    f32x4 acc[4][4];
    #pragma unroll
    for (int i = 0; i < 4; ++i)
        #pragma unroll
        for (int j = 0; j < 4; ++j) acc[i][j] = (f32x4){0.f, 0.f, 0.f, 0.f};

    for (int kt = 0; kt < 16; ++kt) {
        __syncthreads();
        #pragma unroll
        for (int it = 0; it < 2; ++it) {
            int cid = tid + it * 256;
            int row = cid >> 2, c = cid & 3;
            int r = bm + row;
            u16x8 v = {0, 0, 0, 0, 0, 0, 0, 0};
            if (r < Mrows) {
                const unsigned short* src;
                if (r < rb1)      src = a0 + (size_t)r * 512;
                else if (r < rb2) src = a1 + (size_t)(r - rb1) * 512;
                else              src = a2 + (size_t)(r - rb2) * 512;
                v = *(const u16x8*)(src + kt * 32 + c * 8);
            }
            *(u16x8*)&As[row * 40 + c * 8] = v;
            u16x8 wv = *(const u16x8*)(Wt + (size_t)(bn + row) * 512 + kt * 32 + c * 8);
            *(u16x8*)&Ws[row * 40 + c * 8] = wv;
        }
        __syncthreads();

        short8 af[4], bf[4];
        #pragma unroll
        for (int t = 0; t < 4; ++t)
            af[t] = *(const short8*)&As[(wm + t * 16 + l15) * 40 + l4 * 8];
        #pragma unroll
        for (int t = 0; t < 4; ++t)
            bf[t] = *(const short8*)&Ws[(wn + t * 16 + l15) * 40 + l4 * 8];
        #pragma unroll
        for (int tm = 0; tm < 4; ++tm)
            #pragma unroll
            for (int tn = 0; tn < 4; ++tn)
                acc[tm][tn] = __builtin_amdgcn_mfma_f32_16x16x32_bf16(
                    af[tm], bf[tn], acc[tm][tn], 0, 0, 0);
    }

    #pragma unroll
    for (int tm = 0; tm < 4; ++tm) {
        #pragma unroll
        for (int tn = 0; tn < 4; ++tn) {
            const int col = bn + wn + tn * 16 + l15;
            const float bv = bias ? bias[col] : 0.f;
            #pragma unroll
            for (int rr = 0; rr < 4; ++rr) {
                const int row = bm + wm + tm * 16 + l4 * 4 + rr;
                if (row >= Mrows) continue;
                float v = acc[tm][tn][rr] + bv;
                if (mode == 0) {
                    if (row >= clampStart) v = fminf(fmaxf(v, -10.f), 10.f);
                    out0[(size_t)row * 512 + col] = v;
                } else if (mode == 1) {
                    int bb = row & 15, kv = row >> 4;
                    if (col < 512) {
                        out0[(size_t)row * 512 + col] = v;
                        int hh = col >> 6, hd = col & 63;
                        auxU[(((size_t)(bb * 8 + hh)) * 576 + kv) * 64 + hd] = f2b(v);
                    } else {
                        out1[(size_t)row * 512 + (col - 512)] = v;
                        int cc = col - 512, hh = cc >> 6, hd = cc & 63;
                        auxV[(((size_t)(bb * 8 + hh)) * 64 + hd) * 576 + kv] = f2b(v);
                    }
                } else if (mode == 2) {
                    int q = row >> 4, bb = row & 15, hh = col >> 6, hd = col & 63;
                    size_t base = (((size_t)(bb * 8 + hh)) * 576 + q) * 64 + hd;
                    auxU[base] = f2b(v + pbu[col]);
                    auxV[base] = f2b(v + pbv[col]);
                } else {
                    int hh = col >> 6, hd = col & 63;
                    auxU[((size_t)hh * 1023 + row) * 64 + hd] = f2b(v);
                }
            }
        }
    }
}

// ---------------------------------------------------------------------------
// MFMA attention v4: async-DMA triple-buffer pipeline.
// Block = (q-tile 32, n). 4 waves; wave owns rows [mT,mT+16), cols c0..c0+32
// (mod 64) of the score matrix. LDS 63.1 KB -> 2 blocks/CU.
// Staged tiles are unpadded 64x64 bf16 with XOR 16B-group swizzle:
//   LDS(row, g) holds global group g ^ (row&7) of that row.
__global__ __launch_bounds__(256) void attn_mfma_kernel(
    const unsigned short* __restrict__ Qu_g,  // [n][576][64]
    const unsigned short* __restrict__ Qv_g,  // [n][576][64]
    const unsigned short* __restrict__ K_g,   // [n][576][64]
    const unsigned short* __restrict__ VT_g,  // [n][64][576]
    const unsigned short* __restrict__ P_g,   // [8][1023][64]
    const void* __restrict__ maskPtr,
    const int* __restrict__ lengths,
    const int* __restrict__ maskFlags,
    unsigned short* __restrict__ attnT)       // bf16
{
    __shared__ unsigned short stg[3][4096];   // 3 x 8KB rotating
    __shared__ unsigned short sc[32 * 584];
    __shared__ float red[256];
    __shared__ float rowv[32];

    const int qt = blockIdx.x, n = blockIdx.y;
    const int b = n >> 3, h = n & 7;
    const int q0 = qt * 32;
    const int tid = threadIdx.x;
    const int w = tid >> 6, lane = tid & 63;
    const int l15 = lane & 15, l4 = lane >> 4;
    const int lr = lane >> 3, lg = lane & 7;  // DMA: row-in-8, 16B group
    const int mT = (w >> 1) * 16;
    const int c0 = (w & 1) * 32;
    const int t0base = 16 - mT + c0;
    const bool hasBand = (qt >= 1 && qt <= 16);
    const int pbq = 512 - q0;                 // pb = pbq + (kt-1)*64

    const unsigned short* Kn  = K_g  + (size_t)n * 576 * 64;
    const unsigned short* VTn = VT_g + (size_t)n * 64 * 576;
    const unsigned short* Ph  = P_g  + (size_t)h * 1023 * 64;

    short8 quf[2], qvf[2];
    {
        size_t rb = ((size_t)n * 576 + q0 + mT + l15) * 64;
        quf[0] = *(const short8*)&Qu_g[rb + l4 * 8];
        quf[1] = *(const short8*)&Qu_g[rb + 32 + l4 * 8];
        qvf[0] = *(const short8*)&Qv_g[rb + l4 * 8];
        qvf[1] = *(const short8*)&Qv_g[rb + 32 + l4 * 8];
    }

    // ---- DMA issue helpers (2 issues per wave per phase, always) ----
    auto issueK = [&](int kt, int buf) {
        #pragma unroll
        for (int j = 0; j < 2; ++j) {
            int row = w * 16 + j * 8 + lr;
            dma16(Kn + ((size_t)(kt * 64 + row)) * 64 + ((lg ^ (row & 7)) * 8),
                  &stg[buf][(w * 16 + j * 8) * 64]);
        }
    };
    auto issuePa = [&](int kt, int buf) {      // band rows t = 0..63
        int pb = pbq + (kt - 1) * 64;
        #pragma unroll
        for (int j = 0; j < 2; ++j) {
            int row = w * 16 + j * 8 + lr;
            int p = pb + row; p = p < 0 ? 0 : (p > 1022 ? 1022 : p);
            dma16(Ph + (size_t)p * 64 + ((lg ^ (row & 7)) * 8),
                  &stg[buf][(w * 16 + j * 8) * 64]);
        }
    };
    auto issuePb = [&](int kt, int buf) {      // band rows t = 64..95 (x2 dup)
        int pb = pbq + (kt - 1) * 64;
        #pragma unroll
        for (int j = 0; j < 2; ++j) {
            int rl = w * 8 + lr;
            int p = pb + 64 + rl; p = p < 0 ? 0 : (p > 1022 ? 1022 : p);
            dma16(Ph + (size_t)p * 64 + ((lg ^ (rl & 7)) * 8),
                  &stg[buf][(w * 8) * 64]);
        }
    };
    auto issueV = [&](int kt, int buf) {
        #pragma unroll
        for (int j = 0; j < 2; ++j) {
            int row = w * 16 + j * 8 + lr;     // hd
            dma16(VTn + (size_t)row * 576 + kt * 64 + ((lg ^ (row & 7)) * 8),
                  &stg[buf][(w * 16 + j * 8) * 64]);
        }
    };

    // ---- compute helpers ----
    auto computeK = [&](int kt, int buf) {     // AC -> sc (own quadrant)
        #pragma unroll
        for (int s = 0; s < 2; ++s) {
            const int n0 = c0 + s * 16;
            const int rr = n0 + l15;
            f32x4 acc = {0.f, 0.f, 0.f, 0.f};
            #pragma unroll
            for (int kk = 0; kk < 2; ++kk) {
                short8 bfr = *(const short8*)&stg[buf][rr * 64 + (((kk * 4 + l4) ^ (rr & 7)) * 8)];
                acc = __builtin_amdgcn_mfma_f32_16x16x32_bf16(quf[kk], bfr, acc, 0, 0, 0);
            }
            const int col = kt * 64 + n0 + l15;
            #pragma unroll
            for (int r = 0; r < 4; ++r)
                sc[(mT + l4 * 4 + r) * 584 + col] = f2b(acc[r]);
        }
    };
    auto computeP = [&](int kt, int buf, bool hi) {  // BD RMW (own quadrant)
        #pragma unroll
        for (int s = 0; s < 3; ++s) {
            const int t0 = t0base + s * 16;
            if ((!hi && t0 < 64) || (hi && t0 >= 64)) {
                const int tl = (hi ? t0 - 64 : t0) + l15;
                f32x4 acc = {0.f, 0.f, 0.f, 0.f};
                #pragma unroll
                for (int kk = 0; kk < 2; ++kk) {
                    short8 bfr = *(const short8*)&stg[buf][tl * 64 + (((kk * 4 + l4) ^ (tl & 7)) * 8)];
                    acc = __builtin_amdgcn_mfma_f32_16x16x32_bf16(qvf[kk], bfr, acc, 0, 0, 0);
                }
                const int t = t0 + l15;
                #pragma unroll
                for (int r = 0; r < 4; ++r) {
                    const int du = mT + l4 * 4 + r;
                    const int dj = t - 31 + du;
                    if (dj >= c0 && dj < c0 + 32) {
                        const int idx = du * 584 + kt * 64 + dj;
                        sc[idx] = f2b(b2f(sc[idx]) + acc[r]);
                    }
                }
            }
        }
    };

    // ================= scores pipeline =================
    if (hasBand) {
        // phases: p=0 -> K0; p>=1: kt=(p+2)/3, sub=(p+2)%3 (0:K 1:Pa 2:Pb); 25 total
        auto issuePh = [&](int p, int buf) {
            if (p == 0) issueK(0, buf);
            else {
                int kt = (p + 2) / 3, sub = (p + 2) % 3;
                if (sub == 0) issueK(kt, buf);
                else if (sub == 1) issuePa(kt, buf);
                else issuePb(kt, buf);
            }
        };
        issuePh(0, 0);
        issuePh(1, 1);
        #pragma unroll
        for (int p = 0; p < 25; ++p) {
            if (p == 24) asm volatile("s_waitcnt vmcnt(0)" ::: "memory");
            else         asm volatile("s_waitcnt vmcnt(2)" ::: "memory");
            __builtin_amdgcn_s_barrier();
            if (p + 2 < 25) issuePh(p + 2, (p + 2) % 3);
            const int buf = p % 3;
            if (p == 0) computeK(0, buf);
            else {
                int kt = (p + 2) / 3, sub = (p + 2) % 3;
                if (sub == 0) computeK(kt, buf);
                else if (sub == 1) computeP(kt, buf, false);
                else computeP(kt, buf, true);
            }
        }
    } else {
        issueK(0, 0);
        issueK(1, 1);
        #pragma unroll
        for (int p = 0; p < 9; ++p) {
            if (p == 8) asm volatile("s_waitcnt vmcnt(0)" ::: "memory");
            else        asm volatile("s_waitcnt vmcnt(2)" ::: "memory");
            __builtin_amdgcn_s_barrier();
            if (p + 2 < 9) issueK(p + 2, (p + 2) % 3);
            computeK(p, p % 3);
        }
    }
    __syncthreads();

    // ================= softmax =================
    {
        const int row = tid >> 3, seg = tid & 7, cc0 = seg * 72;
        const int q = q0 + row;
        const int padStart = 64 + lengths[b];
        const int mode = maskFlags[0] ? 2 : (maskFlags[1] ? 1 : 0);
        float mx = -3.0e38f;
        unsigned short* sr = &sc[row * 584];
        if (q < 560) {
            if (mode == 1) {
                const unsigned char* mp = (const unsigned char*)maskPtr + (size_t)q * 576;
                for (int c = cc0; c < cc0 + 72; ++c) {
                    float s = b2f(sr[c]) * SCALE_F;
                    if (mp[c] || c >= padStart) s = NEG_INF_F;
                    sr[c] = f2b(s); mx = fmaxf(mx, s);
                }
            } else if (mode == 2) {
                const float* mp = (const float*)maskPtr + (size_t)q * 576;
                for (int c = cc0; c < cc0 + 72; ++c) {
                    float s = b2f(sr[c]) * SCALE_F;
                    if (mp[c] != 0.f || c >= padStart) s = NEG_INF_F;
                    sr[c] = f2b(s); mx = fmaxf(mx, s);
                }
            } else {
                const int* mp = (const int*)maskPtr + (size_t)q * 576;
                for (int c = cc0; c < cc0 + 72; ++c) {
                    float s = b2f(sr[c]) * SCALE_F;
                    if (mp[c] || c >= padStart) s = NEG_INF_F;
                    sr[c] = f2b(s); mx = fmaxf(mx, s);
                }
            }
        } else {
            for (int c = cc0; c < cc0 + 72; ++c) {
                float s = b2f(sr[c]) * SCALE_F;
                sr[c] = f2b(s); mx = fmaxf(mx, s);
            }
        }
        red[row * 8 + seg] = mx;
    }
    __syncthreads();
    if (tid < 32) {
        float m = red[tid * 8];
        #pragma unroll
        for (int i = 1; i < 8; ++i) m = fmaxf(m, red[tid * 8 + i]);
        rowv[tid] = m;
    }
    __syncthreads();
    {
        const int row = tid >> 3, seg = tid & 7, cc0 = seg * 72;
        float mx = rowv[row], lsum = 0.f;
        unsigned short* sr = &sc[row * 584];
        for (int c = cc0; c < cc0 + 72; ++c) {
            float e = __expf(b2f(sr[c]) - mx);
            sr[c] = f2b(e); lsum += e;
        }
        red[row * 8 + seg] = lsum;
    }
    __syncthreads();
    if (tid < 32) {
        float s = 0.f;
        #pragma unroll
        for (int i = 0; i < 8; ++i) s += red[tid * 8 + i];
        rowv[tid] = 1.f / s;
    }
    __syncthreads();

    // ================= PV pipeline =================
    f32x4 oacc[2] = {{0.f, 0.f, 0.f, 0.f}, {0.f, 0.f, 0.f, 0.f}};
    issueV(0, 0);
    issueV(1, 1);
    #pragma unroll
    for (int p = 0; p < 9; ++p) {
        if (p == 8) asm volatile("s_waitcnt vmcnt(0)" ::: "memory");
        else        asm volatile("s_waitcnt vmcnt(2)" ::: "memory");
        __builtin_amdgcn_s_barrier();
        if (p + 2 < 9) issueV(p + 2, (p + 2) % 3);
        const int buf = p % 3;
        #pragma unroll
        for (int s = 0; s < 2; ++s) {
            const int n0 = c0 + s * 16;
            const int rr = n0 + l15;
            #pragma unroll
            for (int kk = 0; kk < 2; ++kk) {
                short8 af = *(const short8*)&sc[(mT + l15) * 584 + p * 64 + kk * 32 + l4 * 8];
                short8 bfr = *(const short8*)&stg[buf][rr * 64 + (((kk * 4 + l4) ^ (rr & 7)) * 8)];
                oacc[s] = __builtin_amdgcn_mfma_f32_16x16x32_bf16(af, bfr, oacc[s], 0, 0, 0);
            }
        }
    }

    // ---- epilogue -> attnT bf16
    #pragma unroll
    for (int s = 0; s < 2; ++s) {
        const int n0 = c0 + s * 16;
        #pragma unroll
        for (int r = 0; r < 4; ++r) {
            const int row = mT + l4 * 4 + r, q = q0 + row;
            if (q < 560)
                attnT[((size_t)q * 16 + b) * 512 + h * 64 + n0 + l15] =
                    f2b(oacc[s][r] * rowv[row]);
        }
    }
}

// ---------------------------------------------------------------------------
extern "C" void kernel_launch(void* const* d_in, const int* in_sizes, int n_in,
                              void* d_out, int out_size, void* d_ws, size_t ws_size,
                              hipStream_t stream) {
    const float* utt     = (const float*)d_in[0];
    const int*   lengths = (const int*)d_in[1];
    const float* rc      = (const float*)d_in[2];
    const float* summ    = (const float*)d_in[3];
    const float* mem     = (const float*)d_in[4];
    const void*  mask    = d_in[5];
    const float* pos_emb = (const float*)d_in[6];
    const float* Wq      = (const float*)d_in[7];
    const float* bq      = (const float*)d_in[8];
    const float* Wkv     = (const float*)d_in[9];
    const float* bkv     = (const float*)d_in[10];
    const float* Wo      = (const float*)d_in[11];
    const float* bo      = (const float*)d_in[12];
    const float* Wpos    = (const float*)d_in[13];
    const float* pbu     = (const float*)d_in[14];
    const float* pbv     = (const float*)d_in[15];

    float* out = (float*)d_out;
    float* out0   = out;
    float* keyOut = out + 4587520;
    float* valOut = out + 9306112;

    int* flags = (int*)d_ws;
    unsigned short* U = (unsigned short*)d_ws + 64;
    unsigned short* utt_bf  = U;
    unsigned short* rc_bf   = utt_bf  + 4194304;
    unsigned short* summ_bf = rc_bf   + 262144;
    unsigned short* mem_bf  = summ_bf + 131072;
    unsigned short* pose_bf = mem_bf  + 262144;
    unsigned short* wq_bf   = pose_bf + 523776;
    unsigned short* wkv_bf  = wq_bf   + 262144;
    unsigned short* wo_bf   = wkv_bf  + 524288;
    unsigned short* wpos_bf = wo_bf   + 262144;
    unsigned short* Qu_bf   = wpos_bf + 262144;
    unsigned short* Qv_bf   = Qu_bf   + 4718592;
    unsigned short* K_bf    = Qv_bf   + 4718592;
    unsigned short* VT_bf   = K_bf    + 4718592;
    unsigned short* posW_bf = VT_bf   + 4718592;
    unsigned short* attnT_bf= posW_bf + 523776;

    hipMemsetAsync(flags, 0, 2 * sizeof(int), stream);
    detect_mask_kernel<<<158, 256, 0, stream>>>((const unsigned int*)mask,
                                                (560 * 576) / 4, flags);

    conv9_kernel<<<dim3(1024, 9), 256, 0, stream>>>(
        utt, rc, summ, mem, pos_emb, Wq, Wkv, Wo, Wpos,
        utt_bf, rc_bf, summ_bf, mem_bf, pose_bf, wq_bf, wkv_bf, wo_bf, wpos_bf,
        4194304, 262144, 131072, 262144, 523776, 262144, 524288, 262144, 262144);

    gemm_mfma<<<dim3(4, 70), 256, 0, stream>>>(
        rc_bf, utt_bf, summ_bf, 512, 8704, 8960, wq_bf, bq,
        nullptr, nullptr, Qu_bf, Qv_bf, pbu, pbv, 2, 0);

    // KV-proj -> keyOut/valOut fp32 + K bf16 + VT bf16 (vt kernel folded in)
    gemm_mfma<<<dim3(8, 72), 256, 0, stream>>>(
        mem_bf, rc_bf, utt_bf, 512, 1024, 9216, wkv_bf, bkv,
        keyOut, valOut, K_bf, VT_bf, nullptr, nullptr, 1, 0);

    gemm_mfma<<<dim3(4, 8), 256, 0, stream>>>(
        pose_bf, pose_bf, pose_bf, 1 << 30, 1 << 30, 1023, wpos_bf, nullptr,
        nullptr, nullptr, posW_bf, nullptr, nullptr, nullptr, 3, 0);

    attn_mfma_kernel<<<dim3(18, 128), 256, 0, stream>>>(
        Qu_bf, Qv_bf, K_bf, VT_bf, posW_bf, mask, lengths, flags, attnT_bf);

    gemm_mfma<<<dim3(4, 70), 256, 0, stream>>>(
        attnT_bf, attnT_bf, attnT_bf, 1 << 30, 1 << 30, 8960, wo_bf, bo,
        out0, nullptr, nullptr, nullptr, nullptr, nullptr, 0, 8704);
}

// Round 6
// 389.336 us; speedup vs baseline: 1.2352x; 1.2352x over previous
//
#include <hip/hip_runtime.h>
#include <math.h>

// EmformerAttention MI355X — round 5: r2-skeleton attention with bf16 bulk
// staging, vectorized softmax, precomputed mask/pad bias (bf16), SCALE folded
// into Qu/Qv. U=512 B=16 D=512 H=8 HD=64 R=32 S=16 M=32 -> Q=560 KV=576 N=128

#define NEG_INF_F (-100000000.0f)
#define SCALE_F   (0.125f)

typedef short  short8 __attribute__((ext_vector_type(8)));
typedef float  f32x4  __attribute__((ext_vector_type(4)));
typedef unsigned short u16x4 __attribute__((ext_vector_type(4)));
typedef unsigned short u16x8 __attribute__((ext_vector_type(8)));

__device__ __forceinline__ unsigned short f2b(float f) {
    unsigned int u = __builtin_bit_cast(unsigned int, f);
    u = u + 0x7FFFu + ((u >> 16) & 1u);
    return (unsigned short)(u >> 16);
}
__device__ __forceinline__ float b2f(unsigned short h) {
    unsigned int u = ((unsigned int)h) << 16;
    return __builtin_bit_cast(float, u);
}

// ---------------------------------------------------------------------------
__global__ __launch_bounds__(256) void detect_mask_kernel(
    const unsigned int* __restrict__ m, int nwords, int* __restrict__ flags) {
    __shared__ int fF, fG;
    if (threadIdx.x == 0) { fF = 0; fG = 0; }
    __syncthreads();
    int lF = 0, lG = 0;
    for (int i = blockIdx.x * 256 + threadIdx.x; i < nwords; i += gridDim.x * 256) {
        unsigned int w = m[i];
        if (w == 0x3F800000u)      lF = 1;
        else if (w > 1u)           lG = 1;
    }
    if (lF) atomicOr(&fF, 1);
    if (lG) atomicOr(&fG, 1);
    __syncthreads();
    if (threadIdx.x == 0) {
        if (fF) atomicOr(&flags[0], 1);
        if (fG) atomicOr(&flags[1], 1);
    }
}

// ---------------------------------------------------------------------------
// Build bf16 additive biases: maskBias[q*576+k] = mask ? -1e8 : 0;
// padBias[b*576+k] = (k >= 64+len[b]) ? -1e8 : 0.
__global__ __launch_bounds__(256) void maskprep_kernel(
    const void* __restrict__ maskPtr, const int* __restrict__ flags,
    const int* __restrict__ lengths,
    unsigned short* __restrict__ maskBias, unsigned short* __restrict__ padBias)
{
    const int mode = flags[0] ? 2 : (flags[1] ? 1 : 0);
    const unsigned short NB = f2b(NEG_INF_F);
    for (int i = blockIdx.x * 256 + threadIdx.x; i < 560 * 576; i += gridDim.x * 256) {
        bool m;
        if (mode == 1)      m = ((const unsigned char*)maskPtr)[i] != 0;
        else if (mode == 2) m = ((const float*)maskPtr)[i] != 0.f;
        else                m = ((const int*)maskPtr)[i] != 0;
        maskBias[i] = m ? NB : (unsigned short)0;
    }
    for (int i = blockIdx.x * 256 + threadIdx.x; i < 16 * 576; i += gridDim.x * 256) {
        int b = i / 576, k = i - b * 576;
        padBias[i] = (k >= 64 + lengths[b]) ? NB : (unsigned short)0;
    }
}

// ---------------------------------------------------------------------------
__global__ __launch_bounds__(256) void conv9_kernel(
    const float* s0, const float* s1, const float* s2, const float* s3,
    const float* s4, const float* s5, const float* s6, const float* s7,
    const float* s8,
    unsigned short* d0, unsigned short* d1, unsigned short* d2,
    unsigned short* d3, unsigned short* d4, unsigned short* d5,
    unsigned short* d6, unsigned short* d7, unsigned short* d8,
    int n0, int n1, int n2, int n3, int n4, int n5, int n6, int n7, int n8)
{
    const float* ss[9] = {s0, s1, s2, s3, s4, s5, s6, s7, s8};
    unsigned short* dd[9] = {d0, d1, d2, d3, d4, d5, d6, d7, d8};
    int nn[9] = {n0, n1, n2, n3, n4, n5, n6, n7, n8};
    const int a = blockIdx.y;
    const float* s = ss[a];
    unsigned short* d = dd[a];
    const int nq = nn[a] >> 2;
    for (int i = blockIdx.x * 256 + threadIdx.x; i < nq; i += gridDim.x * 256) {
        float4 v = *(const float4*)(s + (size_t)i * 4);
        u16x4 o = {f2b(v.x), f2b(v.y), f2b(v.z), f2b(v.w)};
        *(u16x4*)(d + (size_t)i * 4) = o;
    }
}

// ---------------------------------------------------------------------------
// bf16 MFMA GEMM. K=512, BK=32, BM=BN=128, 4 waves.
// mode 0: out-proj (clamp rows>=clampStart); mode 1: KV (key fp32+bf16,
// val fp32 + VT bf16 [n][hd][576]); mode 2: Q (Qu/Qv bf16, *SCALE); mode 3: pos.
__global__ __launch_bounds__(256) void gemm_mfma(
    const unsigned short* __restrict__ a0, const unsigned short* __restrict__ a1,
    const unsigned short* __restrict__ a2,
    int rb1, int rb2, int Mrows,
    const unsigned short* __restrict__ Wt, const float* __restrict__ bias,
    float* __restrict__ out0, float* __restrict__ out1,
    unsigned short* __restrict__ auxU, unsigned short* __restrict__ auxV,
    const float* __restrict__ pbu, const float* __restrict__ pbv,
    int mode, int clampStart)
{
    __shared__ unsigned short As[128 * 40];
    __shared__ unsigned short Ws[128 * 40];

    const int tid = threadIdx.x;
    const int w = tid >> 6, lane = tid & 63;
    const int l15 = lane & 15, l4 = lane >> 4;
    const int wm = (w & 1) * 64, wn = (w >> 1) * 64;
    const int bm = blockIdx.y * 128, bn = blockIdx.x * 128;

    f32x4 acc[4][4];
    #pragma unroll
    for (int i = 0; i < 4; ++i)
        #pragma unroll
        for (int j = 0; j < 4; ++j) acc[i][j] = (f32x4){0.f, 0.f, 0.f, 0.f};

    for (int kt = 0; kt < 16; ++kt) {
        __syncthreads();
        #pragma unroll
        for (int it = 0; it < 2; ++it) {
            int cid = tid + it * 256;
            int row = cid >> 2, c = cid & 3;
            int r = bm + row;
            u16x8 v = {0, 0, 0, 0, 0, 0, 0, 0};
            if (r < Mrows) {
                const unsigned short* src;
                if (r < rb1)      src = a0 + (size_t)r * 512;
                else if (r < rb2) src = a1 + (size_t)(r - rb1) * 512;
                else              src = a2 + (size_t)(r - rb2) * 512;
                v = *(const u16x8*)(src + kt * 32 + c * 8);
            }
            *(u16x8*)&As[row * 40 + c * 8] = v;
            u16x8 wv = *(const u16x8*)(Wt + (size_t)(bn + row) * 512 + kt * 32 + c * 8);
            *(u16x8*)&Ws[row * 40 + c * 8] = wv;
        }
        __syncthreads();

        short8 af[4], bf[4];
        #pragma unroll
        for (int t = 0; t < 4; ++t)
            af[t] = *(const short8*)&As[(wm + t * 16 + l15) * 40 + l4 * 8];
        #pragma unroll
        for (int t = 0; t < 4; ++t)
            bf[t] = *(const short8*)&Ws[(wn + t * 16 + l15) * 40 + l4 * 8];
        #pragma unroll
        for (int tm = 0; tm < 4; ++tm)
            #pragma unroll
            for (int tn = 0; tn < 4; ++tn)
                acc[tm][tn] = __builtin_amdgcn_mfma_f32_16x16x32_bf16(
                    af[tm], bf[tn], acc[tm][tn], 0, 0, 0);
    }

    #pragma unroll
    for (int tm = 0; tm < 4; ++tm) {
        #pragma unroll
        for (int tn = 0; tn < 4; ++tn) {
            const int col = bn + wn + tn * 16 + l15;
            const float bv = bias ? bias[col] : 0.f;
            #pragma unroll
            for (int rr = 0; rr < 4; ++rr) {
                const int row = bm + wm + tm * 16 + l4 * 4 + rr;
                if (row >= Mrows) continue;
                float v = acc[tm][tn][rr] + bv;
                if (mode == 0) {
                    if (row >= clampStart) v = fminf(fmaxf(v, -10.f), 10.f);
                    out0[(size_t)row * 512 + col] = v;
                } else if (mode == 1) {
                    int bb = row & 15, kv = row >> 4;
                    if (col < 512) {
                        out0[(size_t)row * 512 + col] = v;
                        int hh = col >> 6, hd = col & 63;
                        auxU[(((size_t)(bb * 8 + hh)) * 576 + kv) * 64 + hd] = f2b(v);
                    } else {
                        out1[(size_t)row * 512 + (col - 512)] = v;
                        int cc = col - 512, hh = cc >> 6, hd = cc & 63;
                        auxV[(((size_t)(bb * 8 + hh)) * 64 + hd) * 576 + kv] = f2b(v);
                    }
                } else if (mode == 2) {
                    int q = row >> 4, bb = row & 15, hh = col >> 6, hd = col & 63;
                    size_t base = (((size_t)(bb * 8 + hh)) * 576 + q) * 64 + hd;
                    auxU[base] = f2b((v + pbu[col]) * SCALE_F);
                    auxV[base] = f2b((v + pbv[col]) * SCALE_F);
                } else {
                    int hh = col >> 6, hd = col & 63;
                    auxU[((size_t)hh * 1023 + row) * 64 + hd] = f2b(v);
                }
            }
        }
    }
}

// ---------------------------------------------------------------------------
// MFMA attention v5: r2 skeleton, bf16 bulk staging, vectorized softmax with
// precomputed biases. Block = (q-tile 32, n). 4 waves; wave owns rows
// [mT,mT+16) x cols [c0,c0+32) (mod 64). LDS 52.9 KB -> 3 blocks/CU.
__global__ __launch_bounds__(256) void attn_mfma_kernel(
    const unsigned short* __restrict__ Qu_g,  // [n][576][64], pre-scaled
    const unsigned short* __restrict__ Qv_g,  // [n][576][64], pre-scaled
    const unsigned short* __restrict__ K_g,   // [n][576][64]
    const unsigned short* __restrict__ VT_g,  // [n][64][576]
    const unsigned short* __restrict__ P_g,   // [8][1023][64]
    const unsigned short* __restrict__ maskBias, // [560][576] bf16
    const unsigned short* __restrict__ padBias,  // [16][576] bf16
    unsigned short* __restrict__ attnT)       // bf16
{
    __shared__ unsigned short sc[32 * 592];
    __shared__ unsigned short stg[96 * 72];
    __shared__ float red[256];
    __shared__ float rowv[32];

    const int qt = blockIdx.x, n = blockIdx.y;
    const int b = n >> 3, h = n & 7;
    const int q0 = qt * 32;
    const int tid = threadIdx.x;
    const int w = tid >> 6, lane = tid & 63;
    const int l15 = lane & 15, l4 = lane >> 4;
    const int mT = (w >> 1) * 16;
    const int c0 = (w & 1) * 32;
    const int t0base = 16 - mT + c0;
    const bool hasBand = (qt >= 1 && qt <= 16);
    const int pbq = 512 - q0;

    const unsigned short* Kn  = K_g  + (size_t)n * 576 * 64;
    const unsigned short* VTn = VT_g + (size_t)n * 64 * 576;
    const unsigned short* Ph  = P_g  + (size_t)h * 1023 * 64;

    short8 quf[2], qvf[2];
    {
        size_t rb = ((size_t)n * 576 + q0 + mT + l15) * 64;
        quf[0] = *(const short8*)&Qu_g[rb + l4 * 8];
        quf[1] = *(const short8*)&Qu_g[rb + 32 + l4 * 8];
        qvf[0] = *(const short8*)&Qv_g[rb + l4 * 8];
        qvf[1] = *(const short8*)&Qv_g[rb + 32 + l4 * 8];
    }

    // ================= scores =================
    for (int kt = 0; kt < 9; ++kt) {
        __syncthreads();                        // stg free
        #pragma unroll
        for (int it = 0; it < 2; ++it) {
            int cid = tid + it * 256;
            int row = cid >> 3, c = cid & 7;
            u16x8 v = *(const u16x8*)&Kn[((size_t)(kt * 64 + row)) * 64 + c * 8];
            *(u16x8*)&stg[row * 72 + c * 8] = v;
        }
        __syncthreads();
        #pragma unroll
        for (int s = 0; s < 2; ++s) {
            const int n0 = c0 + s * 16;
            f32x4 acc = {0.f, 0.f, 0.f, 0.f};
            #pragma unroll
            for (int kk = 0; kk < 2; ++kk) {
                short8 bfr = *(const short8*)&stg[(n0 + l15) * 72 + kk * 32 + l4 * 8];
                acc = __builtin_amdgcn_mfma_f32_16x16x32_bf16(quf[kk], bfr, acc, 0, 0, 0);
            }
            const int col = kt * 64 + n0 + l15;
            #pragma unroll
            for (int r = 0; r < 4; ++r)
                sc[(mT + l4 * 4 + r) * 592 + col] = f2b(acc[r]);
        }
        if (kt >= 1 && hasBand) {
            __syncthreads();                    // AC frag reads done
            const int pb = pbq + (kt - 1) * 64;
            #pragma unroll
            for (int it = 0; it < 3; ++it) {
                int cid = tid + it * 256;       // 96 rows x 8 chunks
                int row = cid >> 3, c = cid & 7;
                int p = pb + row; p = p < 0 ? 0 : (p > 1022 ? 1022 : p);
                u16x8 v = *(const u16x8*)&Ph[(size_t)p * 64 + c * 8];
                *(u16x8*)&stg[row * 72 + c * 8] = v;
            }
            __syncthreads();
            #pragma unroll
            for (int s = 0; s < 3; ++s) {
                const int t0 = t0base + s * 16;
                const int tl = t0 + l15;        // stg row, 0..95
                f32x4 acc = {0.f, 0.f, 0.f, 0.f};
                #pragma unroll
                for (int kk = 0; kk < 2; ++kk) {
                    short8 bfr = *(const short8*)&stg[tl * 72 + kk * 32 + l4 * 8];
                    acc = __builtin_amdgcn_mfma_f32_16x16x32_bf16(qvf[kk], bfr, acc, 0, 0, 0);
                }
                #pragma unroll
                for (int r = 0; r < 4; ++r) {
                    const int du = mT + l4 * 4 + r;
                    const int dj = tl - 31 + du;
                    if (dj >= c0 && dj < c0 + 32) {
                        const int idx = du * 592 + kt * 64 + dj;
                        sc[idx] = f2b(b2f(sc[idx]) + acc[r]);
                    }
                }
            }
        }
    }
    __syncthreads();

    // ================= softmax (vectorized, branch-free) =================
    {
        const int row = tid >> 3, seg = tid & 7;
        const int q = q0 + row;
        const int qc = q < 560 ? q : 559;       // garbage rows: harmless bias
        unsigned short* sr = &sc[row * 592 + seg * 72];
        const unsigned short* mb = maskBias + (size_t)qc * 576 + seg * 72;
        const unsigned short* pbb = padBias + (size_t)b * 576 + seg * 72;
        float mx = -3.0e38f;
        #pragma unroll
        for (int ci = 0; ci < 9; ++ci) {
            u16x8 sv = *(const u16x8*)&sr[ci * 8];
            u16x8 mv = *(const u16x8*)&mb[ci * 8];
            u16x8 pv = *(const u16x8*)&pbb[ci * 8];
            #pragma unroll
            for (int j = 0; j < 8; ++j)
                mx = fmaxf(mx, b2f(sv[j]) + b2f(mv[j]) + b2f(pv[j]));
        }
        red[row * 8 + seg] = mx;
    }
    __syncthreads();
    if (tid < 32) {
        float m = red[tid * 8];
        #pragma unroll
        for (int i = 1; i < 8; ++i) m = fmaxf(m, red[tid * 8 + i]);
        rowv[tid] = m;
    }
    __syncthreads();
    {
        const int row = tid >> 3, seg = tid & 7;
        const int q = q0 + row;
        const int qc = q < 560 ? q : 559;
        unsigned short* sr = &sc[row * 592 + seg * 72];
        const unsigned short* mb = maskBias + (size_t)qc * 576 + seg * 72;
        const unsigned short* pbb = padBias + (size_t)b * 576 + seg * 72;
        const float mx = rowv[row];
        float lsum = 0.f;
        #pragma unroll
        for (int ci = 0; ci < 9; ++ci) {
            u16x8 sv = *(const u16x8*)&sr[ci * 8];
            u16x8 mv = *(const u16x8*)&mb[ci * 8];
            u16x8 pv = *(const u16x8*)&pbb[ci * 8];
            u16x8 ev;
            #pragma unroll
            for (int j = 0; j < 8; ++j) {
                float e = __expf(b2f(sv[j]) + b2f(mv[j]) + b2f(pv[j]) - mx);
                ev[j] = f2b(e); lsum += e;
            }
            *(u16x8*)&sr[ci * 8] = ev;
        }
        red[row * 8 + seg] = lsum;
    }
    __syncthreads();
    if (tid < 32) {
        float s = 0.f;
        #pragma unroll
        for (int i = 0; i < 8; ++i) s += red[tid * 8 + i];
        rowv[tid] = 1.f / s;
    }
    __syncthreads();

    // ================= PV =================
    f32x4 oacc[2] = {{0.f, 0.f, 0.f, 0.f}, {0.f, 0.f, 0.f, 0.f}};
    for (int kt = 0; kt < 9; ++kt) {
        __syncthreads();                        // stg frag reads done
        #pragma unroll
        for (int it = 0; it < 2; ++it) {
            int cid = tid + it * 256;
            int row = cid >> 3, c = cid & 7;    // row = hd
            u16x8 v = *(const u16x8*)&VTn[(size_t)row * 576 + kt * 64 + c * 8];
            *(u16x8*)&stg[row * 72 + c * 8] = v;
        }
        __syncthreads();
        #pragma unroll
        for (int s = 0; s < 2; ++s) {
            const int n0 = c0 + s * 16;
            #pragma unroll
            for (int kk = 0; kk < 2; ++kk) {
                short8 af = *(const short8*)&sc[(mT + l15) * 592 + kt * 64 + kk * 32 + l4 * 8];
                short8 bfr = *(const short8*)&stg[(n0 + l15) * 72 + kk * 32 + l4 * 8];
                oacc[s] = __builtin_amdgcn_mfma_f32_16x16x32_bf16(af, bfr, oacc[s], 0, 0, 0);
            }
        }
    }

    // ---- epilogue -> attnT bf16
    #pragma unroll
    for (int s = 0; s < 2; ++s) {
        const int n0 = c0 + s * 16;
        #pragma unroll
        for (int r = 0; r < 4; ++r) {
            const int row = mT + l4 * 4 + r, q = q0 + row;
            if (q < 560)
                attnT[((size_t)q * 16 + b) * 512 + h * 64 + n0 + l15] =
                    f2b(oacc[s][r] * rowv[row]);
        }
    }
}

// ---------------------------------------------------------------------------
extern "C" void kernel_launch(void* const* d_in, const int* in_sizes, int n_in,
                              void* d_out, int out_size, void* d_ws, size_t ws_size,
                              hipStream_t stream) {
    const float* utt     = (const float*)d_in[0];
    const int*   lengths = (const int*)d_in[1];
    const float* rc      = (const float*)d_in[2];
    const float* summ    = (const float*)d_in[3];
    const float* mem     = (const float*)d_in[4];
    const void*  mask    = d_in[5];
    const float* pos_emb = (const float*)d_in[6];
    const float* Wq      = (const float*)d_in[7];
    const float* bq      = (const float*)d_in[8];
    const float* Wkv     = (const float*)d_in[9];
    const float* bkv     = (const float*)d_in[10];
    const float* Wo      = (const float*)d_in[11];
    const float* bo      = (const float*)d_in[12];
    const float* Wpos    = (const float*)d_in[13];
    const float* pbu     = (const float*)d_in[14];
    const float* pbv     = (const float*)d_in[15];

    float* out = (float*)d_out;
    float* out0   = out;
    float* keyOut = out + 4587520;
    float* valOut = out + 9306112;

    int* flags = (int*)d_ws;
    unsigned short* U = (unsigned short*)d_ws + 64;
    unsigned short* utt_bf  = U;
    unsigned short* rc_bf   = utt_bf  + 4194304;
    unsigned short* summ_bf = rc_bf   + 262144;
    unsigned short* mem_bf  = summ_bf + 131072;
    unsigned short* pose_bf = mem_bf  + 262144;
    unsigned short* wq_bf   = pose_bf + 523776;
    unsigned short* wkv_bf  = wq_bf   + 262144;
    unsigned short* wo_bf   = wkv_bf  + 524288;
    unsigned short* wpos_bf = wo_bf   + 262144;
    unsigned short* Qu_bf   = wpos_bf + 262144;
    unsigned short* Qv_bf   = Qu_bf   + 4718592;
    unsigned short* K_bf    = Qv_bf   + 4718592;
    unsigned short* VT_bf   = K_bf    + 4718592;
    unsigned short* posW_bf = VT_bf   + 4718592;
    unsigned short* attnT_bf= posW_bf + 523776;
    unsigned short* maskB   = attnT_bf + 4587520;   // 560*576 = 322560
    unsigned short* padB    = maskB + 322560;       // 16*576  = 9216

    hipMemsetAsync(flags, 0, 2 * sizeof(int), stream);
    detect_mask_kernel<<<158, 256, 0, stream>>>((const unsigned int*)mask,
                                                (560 * 576) / 4, flags);
    maskprep_kernel<<<315, 256, 0, stream>>>(mask, flags, lengths, maskB, padB);

    conv9_kernel<<<dim3(1024, 9), 256, 0, stream>>>(
        utt, rc, summ, mem, pos_emb, Wq, Wkv, Wo, Wpos,
        utt_bf, rc_bf, summ_bf, mem_bf, pose_bf, wq_bf, wkv_bf, wo_bf, wpos_bf,
        4194304, 262144, 131072, 262144, 523776, 262144, 524288, 262144, 262144);

    gemm_mfma<<<dim3(4, 70), 256, 0, stream>>>(
        rc_bf, utt_bf, summ_bf, 512, 8704, 8960, wq_bf, bq,
        nullptr, nullptr, Qu_bf, Qv_bf, pbu, pbv, 2, 0);

    gemm_mfma<<<dim3(8, 72), 256, 0, stream>>>(
        mem_bf, rc_bf, utt_bf, 512, 1024, 9216, wkv_bf, bkv,
        keyOut, valOut, K_bf, VT_bf, nullptr, nullptr, 1, 0);

    gemm_mfma<<<dim3(4, 8), 256, 0, stream>>>(
        pose_bf, pose_bf, pose_bf, 1 << 30, 1 << 30, 1023, wpos_bf, nullptr,
        nullptr, nullptr, posW_bf, nullptr, nullptr, nullptr, 3, 0);

    attn_mfma_kernel<<<dim3(18, 128), 256, 0, stream>>>(
        Qu_bf, Qv_bf, K_bf, VT_bf, posW_bf, maskB, padB, attnT_bf);

    gemm_mfma<<<dim3(4, 70), 256, 0, stream>>>(
        attnT_bf, attnT_bf, attnT_bf, 1 << 30, 1 << 30, 8960, wo_bf, bo,
        out0, nullptr, nullptr, nullptr, nullptr, nullptr, 0, 8704);
}